// Round 2
// baseline (1609.412 us; speedup 1.0000x reference)
//
#include <hip/hip_runtime.h>
#include <hip/hip_bf16.h>

// Problem: B=4, T=2048, C=1024, H=16, D=64
#define Bsz 4
#define Tsz 2048
#define Csz 1024
#define NH  16
#define HD  64
#define NT  (Bsz * Tsz)          // 8192 rows

typedef unsigned short u16;
typedef u16   u16x8  __attribute__((ext_vector_type(8)));
typedef short s16x8  __attribute__((ext_vector_type(8)));   // MFMA bf16 A/B frag (4 VGPRs)
typedef float f32x4  __attribute__((ext_vector_type(4)));   // MFMA C/D frag

__device__ __forceinline__ float b2f(u16 u) {
    union { unsigned int i; float f; } x; x.i = ((unsigned int)u) << 16; return x.f;
}
__device__ __forceinline__ u16 f2b(float f) {   // round-to-nearest-even
    unsigned int u = __float_as_uint(f);
    return (u16)((u + 0x7FFF + ((u >> 16) & 1)) >> 16);
}

// ---------------------------------------------------------------------------
// fp32 -> bf16 bulk convert (8 elems/thread)
// ---------------------------------------------------------------------------
__global__ __launch_bounds__(256)
void conv_f32_bf16(const float* __restrict__ in, u16* __restrict__ out, int n8)
{
    int t = blockIdx.x * 256 + threadIdx.x;
    if (t >= n8) return;
    const float4* p = reinterpret_cast<const float4*>(in) + (size_t)t * 2;
    float4 a = p[0], b = p[1];
    u16x8 w;
    w[0] = f2b(a.x); w[1] = f2b(a.y); w[2] = f2b(a.z); w[3] = f2b(a.w);
    w[4] = f2b(b.x); w[5] = f2b(b.y); w[6] = f2b(b.z); w[7] = f2b(b.w);
    *(reinterpret_cast<u16x8*>(out) + t) = w;
}

// ---------------------------------------------------------------------------
// transpose + convert: in [K][N] f32 -> out [N][K] bf16 (32x32 LDS tiles)
// ---------------------------------------------------------------------------
__global__ __launch_bounds__(256)
void transpose_conv(const float* __restrict__ in, u16* __restrict__ out, int K, int N)
{
    __shared__ float tile[32][33];
    const int n0 = blockIdx.x * 32, k0 = blockIdx.y * 32;
    const int tx = threadIdx.x & 31, ty = threadIdx.x >> 5;   // ty 0..7
#pragma unroll
    for (int j = 0; j < 4; ++j)
        tile[ty + j * 8][tx] = in[(size_t)(k0 + ty + j * 8) * N + n0 + tx];
    __syncthreads();
#pragma unroll
    for (int j = 0; j < 4; ++j)
        out[(size_t)(n0 + ty + j * 8) * K + k0 + tx] = f2b(tile[tx][ty + j * 8]);
}

// ---------------------------------------------------------------------------
// bf16 MFMA GEMM: C[M,N] = A[M,K] @ B[K,N] + bias, with B given TRANSPOSED
// (Bt[N][K] bf16). 128x128 tile, BK=64, 256 thr = 4 waves (2x2), each wave
// 64x64 out = 4x4 frags of mfma_f32_16x16x32_bf16. LDS rows are 128 B; slot
// swizzle s_phys = s_log ^ (r&7) makes fragment reads 2-way (free) aliased.
// OutT: u16 (bf16 bits) or float.
// ---------------------------------------------------------------------------
template<typename OutT>
__global__ __launch_bounds__(256)
void gemm_bf16(const u16* __restrict__ A, const u16* __restrict__ Bt,
               const float* __restrict__ bias, OutT* __restrict__ C,
               int M, int N, int K)
{
    __shared__ u16 As[128 * 64];   // 16 KB, [r][64] with swizzled 8-elem slots
    __shared__ u16 Bs[128 * 64];   // 16 KB, rows = output cols

    const int tid  = threadIdx.x;
    const int lane = tid & 63;
    const int wid  = tid >> 6;       // 0..3
    const int wr   = wid >> 1;       // wave row half
    const int wc   = wid & 1;        // wave col half
    const int g    = lane >> 4;      // k-group 0..3
    const int rr   = lane & 15;

    const int n0 = blockIdx.x * 128;
    const int m0 = blockIdx.y * 128;

    f32x4 acc[4][4];
#pragma unroll
    for (int m = 0; m < 4; ++m)
#pragma unroll
        for (int n = 0; n < 4; ++n) acc[m][n] = (f32x4){0.f, 0.f, 0.f, 0.f};

    for (int k0 = 0; k0 < K; k0 += 64) {
        // ---- stage: 1024 chunks of 8 bf16 per operand, 4 passes ----
        s16x8 va[4], vb[4];
#pragma unroll
        for (int p = 0; p < 4; ++p) {
            const int ci = p * 256 + tid;        // 0..1023
            const int r = ci >> 3, s = ci & 7;
            va[p] = *reinterpret_cast<const s16x8*>(A  + (size_t)(m0 + r) * K + k0 + s * 8);
            vb[p] = *reinterpret_cast<const s16x8*>(Bt + (size_t)(n0 + r) * K + k0 + s * 8);
        }
        __syncthreads();   // previous tile's compute done
#pragma unroll
        for (int p = 0; p < 4; ++p) {
            const int ci = p * 256 + tid;
            const int r = ci >> 3, s = ci & 7;
            const int phys = r * 64 + ((s ^ (r & 7)) * 8);
            *reinterpret_cast<s16x8*>(&As[phys]) = va[p];
            *reinterpret_cast<s16x8*>(&Bs[phys]) = vb[p];
        }
        __syncthreads();

        // ---- compute: 2 K-subtiles x 16 MFMAs ----
#pragma unroll
        for (int kk = 0; kk < 2; ++kk) {
            s16x8 af[4], bfr[4];
            const int s = kk * 4 + g;
#pragma unroll
            for (int m = 0; m < 4; ++m) {
                const int r = wr * 64 + m * 16 + rr;
                af[m] = *reinterpret_cast<const s16x8*>(&As[r * 64 + ((s ^ (r & 7)) * 8)]);
            }
#pragma unroll
            for (int n = 0; n < 4; ++n) {
                const int r = wc * 64 + n * 16 + rr;
                bfr[n] = *reinterpret_cast<const s16x8*>(&Bs[r * 64 + ((s ^ (r & 7)) * 8)]);
            }
#pragma unroll
            for (int m = 0; m < 4; ++m)
#pragma unroll
                for (int n = 0; n < 4; ++n)
                    acc[m][n] = __builtin_amdgcn_mfma_f32_16x16x32_bf16(
                        af[m], bfr[n], acc[m][n], 0, 0, 0);
        }
    }

    // ---- epilogue: C/D map col=lane&15, row=(lane>>4)*4+j (m89-verified) ----
#pragma unroll
    for (int m = 0; m < 4; ++m) {
#pragma unroll
        for (int n = 0; n < 4; ++n) {
            const int col = n0 + wc * 64 + n * 16 + rr;
            const float bv = bias[col];
#pragma unroll
            for (int j = 0; j < 4; ++j) {
                const int row = m0 + wr * 64 + m * 16 + g * 4 + j;
                const float v = acc[m][n][j] + bv;
                if constexpr (sizeof(OutT) == 2)
                    C[(size_t)row * N + col] = (OutT)f2b(v);
                else
                    C[(size_t)row * N + col] = (OutT)v;
            }
        }
    }
}

// ---------------------------------------------------------------------------
// Causal flash attention, fp32 math, bf16 I/O. One thread per query row.
// qkv [B*T, 3C] bf16 (q@0, k@C, v@2C, head h at h*HD); out [B*T, C] bf16.
// Block: 128 threads = 128 query rows of one (b,h); 64x64 K/V f32 tiles in LDS.
// ---------------------------------------------------------------------------
__global__ __launch_bounds__(128)
void attn_causal(const u16* __restrict__ qkv, u16* __restrict__ out)
{
    __shared__ float Ks[64][64];
    __shared__ float Vs[64][64];

    const int bh = blockIdx.x;        // 0..63
    const int b  = bh >> 4;
    const int h  = bh & 15;
    const int t0 = blockIdx.y * 128;
    const int tid = threadIdx.x;
    const int qi = t0 + tid;
    const float scale = 0.125f;       // 1/sqrt(64)

    float q[HD];
    {
        const u16* qrow = qkv + (size_t)(b * Tsz + qi) * (3 * Csz) + h * HD;
#pragma unroll
        for (int d = 0; d < HD; d += 8) {
            u16x8 v = *reinterpret_cast<const u16x8*>(qrow + d);
#pragma unroll
            for (int i = 0; i < 8; ++i) q[d + i] = b2f(v[i]);
        }
    }

    float o[HD];
#pragma unroll
    for (int d = 0; d < HD; ++d) o[d] = 0.f;
    float m = -1e30f, l = 0.f;

    const int srow = tid >> 1;            // 2 threads per K/V row
    const int scol = (tid & 1) * 32;
    const int tmax = t0 + 127;

    for (int kt = 0; kt <= tmax; kt += 64) {
        const u16* krow = qkv + (size_t)(b * Tsz + kt + srow) * (3 * Csz)
                          + Csz + h * HD + scol;
        const u16* vrow = krow + Csz;
#pragma unroll
        for (int c = 0; c < 32; c += 8) {
            u16x8 kv = *reinterpret_cast<const u16x8*>(krow + c);
            u16x8 vv = *reinterpret_cast<const u16x8*>(vrow + c);
#pragma unroll
            for (int i = 0; i < 8; ++i) {
                Ks[srow][scol + c + i] = b2f(kv[i]);
                Vs[srow][scol + c + i] = b2f(vv[i]);
            }
        }
        __syncthreads();

        const int jmax = min(64, qi - kt + 1);    // causal
        for (int j = 0; j < jmax; ++j) {
            float s = 0.f;
#pragma unroll
            for (int d = 0; d < HD; d += 4) {
                float4 kv = *reinterpret_cast<const float4*>(&Ks[j][d]);
                s += q[d + 0] * kv.x + q[d + 1] * kv.y
                   + q[d + 2] * kv.z + q[d + 3] * kv.w;
            }
            s *= scale;
            if (s > m) {
                const float corr = __expf(m - s);
                l *= corr;
#pragma unroll
                for (int d = 0; d < HD; ++d) o[d] *= corr;
                m = s;
            }
            const float p = __expf(s - m);
            l += p;
#pragma unroll
            for (int d = 0; d < HD; d += 4) {
                float4 vv = *reinterpret_cast<const float4*>(&Vs[j][d]);
                o[d + 0] += p * vv.x; o[d + 1] += p * vv.y;
                o[d + 2] += p * vv.z; o[d + 3] += p * vv.w;
            }
        }
        __syncthreads();
    }

    const float inv = 1.f / l;
    u16* orow = out + (size_t)(b * Tsz + qi) * Csz + h * HD;
#pragma unroll
    for (int d = 0; d < HD; d += 8) {
        u16x8 w;
#pragma unroll
        for (int i = 0; i < 8; ++i) w[i] = f2b(o[d + i] * inv);
        *reinterpret_cast<u16x8*>(orow + d) = w;
    }
}

// ---------------------------------------------------------------------------
extern "C" void kernel_launch(void* const* d_in, const int* in_sizes, int n_in,
                              void* d_out, int out_size, void* d_ws, size_t ws_size,
                              hipStream_t stream) {
    const float* x      = (const float*)d_in[0];   // [B,T,C]
    const float* w_attn = (const float*)d_in[1];   // [C,3C]
    const float* b_attn = (const float*)d_in[2];   // [3C]
    const float* w_proj = (const float*)d_in[3];   // [C,C]
    const float* b_proj = (const float*)d_in[4];   // [C]
    float* out = (float*)d_out;                    // [B,T,C] fp32

    // ws layout (88 MiB total):
    //   qkv_bf [NT,3C] 48M | x_bf [NT,C] 16M | ao_bf [NT,C] 16M
    //   wat [3C,C] 6M | wpt [C,C] 2M
    char* w = (char*)d_ws;
    u16* qkv_bf = (u16*)w;  w += (size_t)NT * 3 * Csz * 2;
    u16* x_bf   = (u16*)w;  w += (size_t)NT * Csz * 2;
    u16* ao_bf  = (u16*)w;  w += (size_t)NT * Csz * 2;
    u16* wat    = (u16*)w;  w += (size_t)3 * Csz * Csz * 2;
    u16* wpt    = (u16*)w;

    // 1) dtype conversions / weight transposes
    conv_f32_bf16<<<(NT * Csz / 8 + 255) / 256, 256, 0, stream>>>(x, x_bf, NT * Csz / 8);
    transpose_conv<<<dim3(3 * Csz / 32, Csz / 32), 256, 0, stream>>>(w_attn, wat, Csz, 3 * Csz);
    transpose_conv<<<dim3(Csz / 32, Csz / 32), 256, 0, stream>>>(w_proj, wpt, Csz, Csz);

    // 2) qkv = x @ w_attn + b_attn    (bf16 out)
    gemm_bf16<u16><<<dim3(3 * Csz / 128, NT / 128), 256, 0, stream>>>(
        x_bf, wat, b_attn, qkv_bf, NT, 3 * Csz, Csz);

    // 3) causal attention (bf16 out, [B,T,H,D] == [NT,C])
    attn_causal<<<dim3(Bsz * NH, Tsz / 128), 128, 0, stream>>>(qkv_bf, ao_bf);

    // 4) out = attout @ w_proj + b_proj   (fp32 out)
    gemm_bf16<float><<<dim3(Csz / 128, NT / 128), 256, 0, stream>>>(
        ao_bf, wpt, b_proj, out, NT, Csz, Csz);
}

// Round 3
// 306.596 us; speedup vs baseline: 5.2493x; 5.2493x over previous
//
#include <hip/hip_runtime.h>
#include <hip/hip_bf16.h>

// Problem: B=4, T=2048, C=1024, H=16, D=64
#define Bsz 4
#define Tsz 2048
#define Csz 1024
#define NH  16
#define HD  64
#define NT  (Bsz * Tsz)          // 8192 rows

typedef unsigned short u16;
typedef unsigned int   u32;
typedef u16   u16x8  __attribute__((ext_vector_type(8)));
typedef u16   u16x4  __attribute__((ext_vector_type(4)));
typedef short s16x8  __attribute__((ext_vector_type(8)));   // MFMA bf16 A/B frag (4 VGPRs)
typedef float f32x4  __attribute__((ext_vector_type(4)));   // MFMA C/D frag

__device__ __forceinline__ float b2f(u16 u) {
    union { unsigned int i; float f; } x; x.i = ((unsigned int)u) << 16; return x.f;
}
__device__ __forceinline__ u16 f2b(float f) {   // round-to-nearest-even
    unsigned int u = __float_as_uint(f);
    return (u16)((u + 0x7FFF + ((u >> 16) & 1)) >> 16);
}
__device__ __forceinline__ float ex2(float x) {  // 2^x via v_exp_f32
    float r; asm("v_exp_f32 %0, %1" : "=v"(r) : "v"(x)); return r;
}

// ---------------------------------------------------------------------------
// fp32 -> bf16 bulk convert (8 elems/thread)
// ---------------------------------------------------------------------------
__global__ __launch_bounds__(256)
void conv_f32_bf16(const float* __restrict__ in, u16* __restrict__ out, int n8)
{
    int t = blockIdx.x * 256 + threadIdx.x;
    if (t >= n8) return;
    const float4* p = reinterpret_cast<const float4*>(in) + (size_t)t * 2;
    float4 a = p[0], b = p[1];
    u16x8 w;
    w[0] = f2b(a.x); w[1] = f2b(a.y); w[2] = f2b(a.z); w[3] = f2b(a.w);
    w[4] = f2b(b.x); w[5] = f2b(b.y); w[6] = f2b(b.z); w[7] = f2b(b.w);
    *(reinterpret_cast<u16x8*>(out) + t) = w;
}

// ---------------------------------------------------------------------------
// transpose + convert: in [K][N] f32 -> out [N][K] bf16 (32x32 LDS tiles)
// ---------------------------------------------------------------------------
__global__ __launch_bounds__(256)
void transpose_conv(const float* __restrict__ in, u16* __restrict__ out, int K, int N)
{
    __shared__ float tile[32][33];
    const int n0 = blockIdx.x * 32, k0 = blockIdx.y * 32;
    const int tx = threadIdx.x & 31, ty = threadIdx.x >> 5;   // ty 0..7
#pragma unroll
    for (int j = 0; j < 4; ++j)
        tile[ty + j * 8][tx] = in[(size_t)(k0 + ty + j * 8) * N + n0 + tx];
    __syncthreads();
#pragma unroll
    for (int j = 0; j < 4; ++j)
        out[(size_t)(n0 + ty + j * 8) * K + k0 + tx] = f2b(tile[tx][ty + j * 8]);
}

// ---------------------------------------------------------------------------
// bf16 MFMA GEMM (unchanged from round 2 — passed): C = A @ B + bias, B given
// transposed (Bt[N][K]). 128x128 tile, BK=64, 4 waves (2x2).
// ---------------------------------------------------------------------------
template<typename OutT>
__global__ __launch_bounds__(256)
void gemm_bf16(const u16* __restrict__ A, const u16* __restrict__ Bt,
               const float* __restrict__ bias, OutT* __restrict__ C,
               int M, int N, int K)
{
    __shared__ u16 As[128 * 64];
    __shared__ u16 Bs[128 * 64];

    const int tid  = threadIdx.x;
    const int lane = tid & 63;
    const int wid  = tid >> 6;
    const int wr   = wid >> 1;
    const int wc   = wid & 1;
    const int g    = lane >> 4;
    const int rr   = lane & 15;

    const int n0 = blockIdx.x * 128;
    const int m0 = blockIdx.y * 128;

    f32x4 acc[4][4];
#pragma unroll
    for (int m = 0; m < 4; ++m)
#pragma unroll
        for (int n = 0; n < 4; ++n) acc[m][n] = (f32x4){0.f, 0.f, 0.f, 0.f};

    for (int k0 = 0; k0 < K; k0 += 64) {
        s16x8 va[4], vb[4];
#pragma unroll
        for (int p = 0; p < 4; ++p) {
            const int ci = p * 256 + tid;
            const int r = ci >> 3, s = ci & 7;
            va[p] = *reinterpret_cast<const s16x8*>(A  + (size_t)(m0 + r) * K + k0 + s * 8);
            vb[p] = *reinterpret_cast<const s16x8*>(Bt + (size_t)(n0 + r) * K + k0 + s * 8);
        }
        __syncthreads();
#pragma unroll
        for (int p = 0; p < 4; ++p) {
            const int ci = p * 256 + tid;
            const int r = ci >> 3, s = ci & 7;
            const int phys = r * 64 + ((s ^ (r & 7)) * 8);
            *reinterpret_cast<s16x8*>(&As[phys]) = va[p];
            *reinterpret_cast<s16x8*>(&Bs[phys]) = vb[p];
        }
        __syncthreads();

#pragma unroll
        for (int kk = 0; kk < 2; ++kk) {
            s16x8 af[4], bfr[4];
            const int s = kk * 4 + g;
#pragma unroll
            for (int m = 0; m < 4; ++m) {
                const int r = wr * 64 + m * 16 + rr;
                af[m] = *reinterpret_cast<const s16x8*>(&As[r * 64 + ((s ^ (r & 7)) * 8)]);
            }
#pragma unroll
            for (int n = 0; n < 4; ++n) {
                const int r = wc * 64 + n * 16 + rr;
                bfr[n] = *reinterpret_cast<const s16x8*>(&Bs[r * 64 + ((s ^ (r & 7)) * 8)]);
            }
#pragma unroll
            for (int m = 0; m < 4; ++m)
#pragma unroll
                for (int n = 0; n < 4; ++n)
                    acc[m][n] = __builtin_amdgcn_mfma_f32_16x16x32_bf16(
                        af[m], bfr[n], acc[m][n], 0, 0, 0);
        }
    }

#pragma unroll
    for (int m = 0; m < 4; ++m) {
#pragma unroll
        for (int n = 0; n < 4; ++n) {
            const int col = n0 + wc * 64 + n * 16 + rr;
            const float bv = bias[col];
#pragma unroll
            for (int j = 0; j < 4; ++j) {
                const int row = m0 + wr * 64 + m * 16 + g * 4 + j;
                const float v = acc[m][n][j] + bv;
                if constexpr (sizeof(OutT) == 2)
                    C[(size_t)row * N + col] = (OutT)f2b(v);
                else
                    C[(size_t)row * N + col] = (OutT)v;
            }
        }
    }
}

// ---------------------------------------------------------------------------
// MFMA causal flash attention.
// Block = 256 thr = 4 waves; each wave owns 32 query rows of one (b,h).
// KV tiles of 64 keys staged in LDS: K row-major XOR-swizzled; V transposed
// (Vt[d][key]) with (d&7)^((d>>3)&7) swizzle -> all MFMA frag reads are b128
// at 2-way (free) bank aliasing. P goes through a wave-private LDS buffer in
// a slot layout built so ds_read_b64_tr_b16 reconstructs exact A-fragments.
// ---------------------------------------------------------------------------
__global__ __launch_bounds__(256)
void attn_mfma(const u16* __restrict__ qkv, u16* __restrict__ out)
{
    __shared__ __align__(128) u16 Ks[64 * 64];    // 8 KB
    __shared__ __align__(128) u16 Vt[64 * 64];    // 8 KB
    __shared__ __align__(128) u16 Pl[4 * 2048];   // 16 KB (4 KB per wave)

    const int tid  = threadIdx.x;
    const int lane = tid & 63;
    const int wid  = tid >> 6;
    const int c    = lane & 15;       // frag col / row-within-16
    const int g    = lane >> 4;       // k-group 0..3

    const int bh = blockIdx.x;        // 0..63
    const int b  = bh >> 4;
    const int h  = bh & 15;
    const int t0 = ((int)gridDim.y - 1 - (int)blockIdx.y) * 128;  // heavy blocks first
    const int qb0 = t0 + wid * 32;    // this wave's first query row

    // ---- Q fragments (A-operand): row=c, k=g*8+j, per (m, kk) ----
    s16x8 qf[2][2];
#pragma unroll
    for (int m = 0; m < 2; ++m)
#pragma unroll
        for (int kk = 0; kk < 2; ++kk)
            qf[m][kk] = *reinterpret_cast<const s16x8*>(
                qkv + (size_t)(b * Tsz + qb0 + m * 16 + c) * (3 * Csz) + h * HD + kk * 32 + g * 8);

    f32x4 acco[2][4];
#pragma unroll
    for (int m = 0; m < 2; ++m)
#pragma unroll
        for (int dn = 0; dn < 4; ++dn) acco[m][dn] = (f32x4){0.f, 0.f, 0.f, 0.f};
    float mrun[8], lrun[8];
#pragma unroll
    for (int i = 0; i < 8; ++i) { mrun[i] = -1e30f; lrun[i] = 0.f; }

    const int skey = tid >> 3;        // staging: key row 0..31 (+32 second pass)
    const int sb   = tid & 7;         // staging: 16B d-block 0..7
    const u32 pbyte = ((u32)(size_t)(&Pl[0])) + wid * 4096 + lane * 8;
    const float SC = 0.18033688f;     // 0.125 * log2(e)

    for (int kt = 0; kt < t0 + 128; kt += 64) {
        // ---- stage K (swizzled b128) + V (transposed scatter, swizzled) ----
#pragma unroll
        for (int p = 0; p < 2; ++p) {
            const int key = skey + p * 32;
            const u16* gk = qkv + (size_t)(b * Tsz + kt + key) * (3 * Csz) + Csz + h * HD + sb * 8;
            u16x8 kv = *reinterpret_cast<const u16x8*>(gk);
            u16x8 vv = *reinterpret_cast<const u16x8*>(gk + Csz);
            *reinterpret_cast<u16x8*>(&Ks[key * 64 + ((sb ^ (key & 7)) * 8)]) = kv;
#pragma unroll
            for (int i = 0; i < 8; ++i) {
                const int d = sb * 8 + i;                       // swz(d) = (d&7)^((d>>3)&7) = i^sb
                Vt[d * 64 + (key ^ (((i ^ sb) & 7) << 3))] = vv[i];
            }
        }
        __syncthreads();

        if (kt <= qb0 + 31) {         // wave-uniform: skip fully-masked tiles
            // ---- S = Q K^T (raw, unscaled) ----
            f32x4 accS[2][4];
#pragma unroll
            for (int m = 0; m < 2; ++m)
#pragma unroll
                for (int n = 0; n < 4; ++n) accS[m][n] = (f32x4){0.f, 0.f, 0.f, 0.f};
#pragma unroll
            for (int kk = 0; kk < 2; ++kk) {
                s16x8 kf[4];
#pragma unroll
                for (int n = 0; n < 4; ++n) {
                    const int key = n * 16 + c;
                    kf[n] = *reinterpret_cast<const s16x8*>(
                        &Ks[key * 64 + (((kk * 4 + g) ^ (c & 7)) * 8)]);
                }
#pragma unroll
                for (int m = 0; m < 2; ++m)
#pragma unroll
                    for (int n = 0; n < 4; ++n)
                        accS[m][n] = __builtin_amdgcn_mfma_f32_16x16x32_bf16(
                            qf[m][kk], kf[n], accS[m][n], 0, 0, 0);
            }

            // ---- causal mask (diagonal tiles only) ----
            if (kt + 63 > qb0) {
#pragma unroll
                for (int m = 0; m < 2; ++m)
#pragma unroll
                    for (int n = 0; n < 4; ++n) {
                        const int kgl = kt + n * 16 + c;
#pragma unroll
                        for (int j = 0; j < 4; ++j) {
                            const int qg = qb0 + m * 16 + g * 4 + j;
                            if (kgl > qg) accS[m][n][j] = -1e30f;
                        }
                    }
            }

            // ---- online softmax (rows live across lanes sharing lane>>4) ----
            float pm[8];
#pragma unroll
            for (int m = 0; m < 2; ++m)
#pragma unroll
                for (int j = 0; j < 4; ++j)
                    pm[m * 4 + j] = fmaxf(fmaxf(accS[m][0][j], accS[m][1][j]),
                                          fmaxf(accS[m][2][j], accS[m][3][j]));
#pragma unroll
            for (int msk = 1; msk < 16; msk <<= 1)
#pragma unroll
                for (int i = 0; i < 8; ++i)
                    pm[i] = fmaxf(pm[i], __shfl_xor(pm[i], msk));
            float cvec[8];
#pragma unroll
            for (int i = 0; i < 8; ++i) {
                const float mn = fmaxf(mrun[i], pm[i]);
                cvec[i] = ex2((mrun[i] - mn) * SC);
                mrun[i] = mn;
                lrun[i] *= cvec[i];
            }
#pragma unroll
            for (int m = 0; m < 2; ++m)
#pragma unroll
                for (int dn = 0; dn < 4; ++dn)
#pragma unroll
                    for (int j = 0; j < 4; ++j)
                        acco[m][dn][j] *= cvec[m * 4 + j];

            // ---- P = 2^((S-m)*SC); bf16; store in tr-read slot layout ----
#pragma unroll
            for (int m = 0; m < 2; ++m)
#pragma unroll
                for (int n = 0; n < 4; ++n) {
                    u16x4 pb;
#pragma unroll
                    for (int j = 0; j < 4; ++j) {
                        const float p = ex2((accS[m][n][j] - mrun[m * 4 + j]) * SC);
                        lrun[m * 4 + j] += p;
                        pb[j] = f2b(p);
                    }
                    // key = n*16+c -> slot = kk*32 + hi*16 + gr*4 + (key&3)
                    const int slot = (n >> 1) * 32 + ((c >> 2) & 1) * 16
                                   + ((n & 1) * 2 + (c >> 3)) * 4 + (c & 3);
                    *reinterpret_cast<u16x4*>(&Pl[wid * 2048 + m * 1024 + slot * 16 + g * 4]) = pb;
                }
            asm volatile("s_waitcnt lgkmcnt(0)" ::: "memory");
            __builtin_amdgcn_sched_barrier(0);

            // ---- hardware transpose reads: P A-frags ----
            u16x4 t000, t001, t010, t011, t100, t101, t110, t111;
            asm volatile("ds_read_b64_tr_b16 %0, %1"             : "=v"(t000) : "v"(pbyte));
            asm volatile("ds_read_b64_tr_b16 %0, %1 offset:512"  : "=v"(t001) : "v"(pbyte));
            asm volatile("ds_read_b64_tr_b16 %0, %1 offset:1024" : "=v"(t010) : "v"(pbyte));
            asm volatile("ds_read_b64_tr_b16 %0, %1 offset:1536" : "=v"(t011) : "v"(pbyte));
            asm volatile("ds_read_b64_tr_b16 %0, %1 offset:2048" : "=v"(t100) : "v"(pbyte));
            asm volatile("ds_read_b64_tr_b16 %0, %1 offset:2560" : "=v"(t101) : "v"(pbyte));
            asm volatile("ds_read_b64_tr_b16 %0, %1 offset:3072" : "=v"(t110) : "v"(pbyte));
            asm volatile("ds_read_b64_tr_b16 %0, %1 offset:3584" : "=v"(t111) : "v"(pbyte));
            asm volatile("s_waitcnt lgkmcnt(0)" ::: "memory");
            __builtin_amdgcn_sched_barrier(0);

            s16x8 pa[2][2];
#pragma unroll
            for (int q = 0; q < 4; ++q) {
                pa[0][0][q] = (short)t000[q]; pa[0][0][q + 4] = (short)t001[q];
                pa[0][1][q] = (short)t010[q]; pa[0][1][q + 4] = (short)t011[q];
                pa[1][0][q] = (short)t100[q]; pa[1][0][q + 4] = (short)t101[q];
                pa[1][1][q] = (short)t110[q]; pa[1][1][q + 4] = (short)t111[q];
            }

            // ---- O += P V ----
#pragma unroll
            for (int kk = 0; kk < 2; ++kk) {
                s16x8 vf[4];
#pragma unroll
                for (int dn = 0; dn < 4; ++dn) {
                    const int d = dn * 16 + c;
                    const int swz = (c & 7) ^ ((dn * 2 + (c >> 3)) & 7);
                    vf[dn] = *reinterpret_cast<const s16x8*>(
                        &Vt[d * 64 + (((kk * 4 + g) ^ swz) * 8)]);
                }
#pragma unroll
                for (int m = 0; m < 2; ++m)
#pragma unroll
                    for (int dn = 0; dn < 4; ++dn)
                        acco[m][dn] = __builtin_amdgcn_mfma_f32_16x16x32_bf16(
                            pa[m][kk], vf[dn], acco[m][dn], 0, 0, 0);
            }
        }
        __syncthreads();
    }

    // ---- finalize: reduce l across the 16-lane groups, normalize, store ----
#pragma unroll
    for (int msk = 1; msk < 16; msk <<= 1)
#pragma unroll
        for (int i = 0; i < 8; ++i)
            lrun[i] += __shfl_xor(lrun[i], msk);
    float inv[8];
#pragma unroll
    for (int i = 0; i < 8; ++i) inv[i] = 1.f / lrun[i];
#pragma unroll
    for (int m = 0; m < 2; ++m)
#pragma unroll
        for (int dn = 0; dn < 4; ++dn)
#pragma unroll
            for (int j = 0; j < 4; ++j) {
                const int q = qb0 + m * 16 + g * 4 + j;
                out[(size_t)(b * Tsz + q) * Csz + h * HD + dn * 16 + c] =
                    f2b(acco[m][dn][j] * inv[m * 4 + j]);
            }
}

// ---------------------------------------------------------------------------
extern "C" void kernel_launch(void* const* d_in, const int* in_sizes, int n_in,
                              void* d_out, int out_size, void* d_ws, size_t ws_size,
                              hipStream_t stream) {
    const float* x      = (const float*)d_in[0];   // [B,T,C]
    const float* w_attn = (const float*)d_in[1];   // [C,3C]
    const float* b_attn = (const float*)d_in[2];   // [3C]
    const float* w_proj = (const float*)d_in[3];   // [C,C]
    const float* b_proj = (const float*)d_in[4];   // [C]
    float* out = (float*)d_out;                    // [B,T,C] fp32

    // ws: qkv_bf 48M | x_bf 16M | ao_bf 16M | wat 6M | wpt 2M
    char* w = (char*)d_ws;
    u16* qkv_bf = (u16*)w;  w += (size_t)NT * 3 * Csz * 2;
    u16* x_bf   = (u16*)w;  w += (size_t)NT * Csz * 2;
    u16* ao_bf  = (u16*)w;  w += (size_t)NT * Csz * 2;
    u16* wat    = (u16*)w;  w += (size_t)3 * Csz * Csz * 2;
    u16* wpt    = (u16*)w;

    conv_f32_bf16<<<(NT * Csz / 8 + 255) / 256, 256, 0, stream>>>(x, x_bf, NT * Csz / 8);
    transpose_conv<<<dim3(3 * Csz / 32, Csz / 32), 256, 0, stream>>>(w_attn, wat, Csz, 3 * Csz);
    transpose_conv<<<dim3(Csz / 32, Csz / 32), 256, 0, stream>>>(w_proj, wpt, Csz, Csz);

    gemm_bf16<u16><<<dim3(3 * Csz / 128, NT / 128), 256, 0, stream>>>(
        x_bf, wat, b_attn, qkv_bf, NT, 3 * Csz, Csz);

    attn_mfma<<<dim3(Bsz * NH, Tsz / 128), 256, 0, stream>>>(qkv_bf, ao_bf);

    gemm_bf16<float><<<dim3(Csz / 128, NT / 128), 256, 0, stream>>>(
        ao_bf, wpt, b_proj, out, NT, Csz, Csz);
}

// Round 4
// 299.918 us; speedup vs baseline: 5.3662x; 1.0223x over previous
//
#include <hip/hip_runtime.h>
#include <hip/hip_bf16.h>

// Problem: B=4, T=2048, C=1024, H=16, D=64
#define Bsz 4
#define Tsz 2048
#define Csz 1024
#define NH  16
#define HD  64
#define NT  (Bsz * Tsz)          // 8192 rows

typedef unsigned short u16;
typedef unsigned int   u32;
typedef u16   u16x8  __attribute__((ext_vector_type(8)));
typedef u16   u16x4  __attribute__((ext_vector_type(4)));
typedef u32   u32x2  __attribute__((ext_vector_type(2)));
typedef short s16x8  __attribute__((ext_vector_type(8)));   // MFMA bf16 A/B frag (4 VGPRs)
typedef float f32x4  __attribute__((ext_vector_type(4)));   // MFMA C/D frag

__device__ __forceinline__ float b2f(u16 u) {
    union { unsigned int i; float f; } x; x.i = ((unsigned int)u) << 16; return x.f;
}
__device__ __forceinline__ u16 f2b(float f) {   // round-to-nearest-even
    unsigned int u = __float_as_uint(f);
    return (u16)((u + 0x7FFF + ((u >> 16) & 1)) >> 16);
}
__device__ __forceinline__ float ex2(float x) {  // 2^x via v_exp_f32
    float r; asm("v_exp_f32 %0, %1" : "=v"(r) : "v"(x)); return r;
}
__device__ __forceinline__ u32 cvtpk(float lo, float hi) {  // bf16(lo) | bf16(hi)<<16
    u32 r; asm("v_cvt_pk_bf16_f32 %0, %1, %2" : "=v"(r) : "v"(lo), "v"(hi)); return r;
}
// async global->LDS, 16B per lane; LDS dest = wave-uniform base + lane*16
__device__ __forceinline__ void gload16(const u16* g, u16* l) {
    __builtin_amdgcn_global_load_lds(
        (const __attribute__((address_space(1))) void*)g,
        (__attribute__((address_space(3))) void*)l, 16, 0, 0);
}

// ---------------------------------------------------------------------------
// fp32 -> bf16 bulk convert (8 elems/thread)
// ---------------------------------------------------------------------------
__global__ __launch_bounds__(256)
void conv_f32_bf16(const float* __restrict__ in, u16* __restrict__ out, int n8)
{
    int t = blockIdx.x * 256 + threadIdx.x;
    if (t >= n8) return;
    const float4* p = reinterpret_cast<const float4*>(in) + (size_t)t * 2;
    float4 a = p[0], b = p[1];
    u16x8 w;
    w[0] = f2b(a.x); w[1] = f2b(a.y); w[2] = f2b(a.z); w[3] = f2b(a.w);
    w[4] = f2b(b.x); w[5] = f2b(b.y); w[6] = f2b(b.z); w[7] = f2b(b.w);
    *(reinterpret_cast<u16x8*>(out) + t) = w;
}

// ---------------------------------------------------------------------------
// transpose + convert: in [K][N] f32 -> out [N][K] bf16 (32x32 LDS tiles)
// ---------------------------------------------------------------------------
__global__ __launch_bounds__(256)
void transpose_conv(const float* __restrict__ in, u16* __restrict__ out, int K, int N)
{
    __shared__ float tile[32][33];
    const int n0 = blockIdx.x * 32, k0 = blockIdx.y * 32;
    const int tx = threadIdx.x & 31, ty = threadIdx.x >> 5;   // ty 0..7
#pragma unroll
    for (int j = 0; j < 4; ++j)
        tile[ty + j * 8][tx] = in[(size_t)(k0 + ty + j * 8) * N + n0 + tx];
    __syncthreads();
#pragma unroll
    for (int j = 0; j < 4; ++j)
        out[(size_t)(n0 + ty + j * 8) * K + k0 + tx] = f2b(tile[tx][ty + j * 8]);
}

// ---------------------------------------------------------------------------
// bf16 MFMA GEMM, m97 structure: global_load_lds(16B) staging into LINEAR LDS,
// 2-barrier K-loop. C = A @ B + bias, B given transposed (Bt[N][K]).
// 128x128 tile, BK=64, 4 waves (2x2), 4x4 frags of mfma_f32_16x16x32_bf16.
// ---------------------------------------------------------------------------
template<typename OutT>
__global__ __launch_bounds__(256)
void gemm_bf16(const u16* __restrict__ A, const u16* __restrict__ Bt,
               const float* __restrict__ bias, OutT* __restrict__ C,
               int M, int N, int K)
{
    __shared__ u16 As[128 * 64];   // 16 KB, linear [row][64]
    __shared__ u16 Bs[128 * 64];   // 16 KB, rows = output cols

    const int tid  = threadIdx.x;
    const int lane = tid & 63;
    const int wid  = tid >> 6;
    const int wr   = wid >> 1;
    const int wc   = wid & 1;
    const int g    = lane >> 4;
    const int rr   = lane & 15;
    const int srow = lane >> 3;      // staging: row-within-chunk 0..7
    const int sslt = lane & 7;       // staging: 16B slot 0..7

    const int n0 = blockIdx.x * 128;
    const int m0 = blockIdx.y * 128;

    f32x4 acc[4][4];
#pragma unroll
    for (int m = 0; m < 4; ++m)
#pragma unroll
        for (int n = 0; n < 4; ++n) acc[m][n] = (f32x4){0.f, 0.f, 0.f, 0.f};

    for (int k0 = 0; k0 < K; k0 += 64) {
        __syncthreads();             // prev tile's compute done
#pragma unroll
        for (int p = 0; p < 4; ++p) {
            const int q = p * 4 + wid;          // chunk 0..15 (8 rows each)
            const int r = q * 8 + srow;
            gload16(A  + (size_t)(m0 + r) * K + k0 + sslt * 8, &As[q * 512]);
            gload16(Bt + (size_t)(n0 + r) * K + k0 + sslt * 8, &Bs[q * 512]);
        }
        __syncthreads();             // compiler drains vmcnt before barrier

#pragma unroll
        for (int kk = 0; kk < 2; ++kk) {
            s16x8 af[4], bfr[4];
            const int s = kk * 4 + g;
#pragma unroll
            for (int m = 0; m < 4; ++m)
                af[m] = *reinterpret_cast<const s16x8*>(
                    &As[(wr * 64 + m * 16 + rr) * 64 + s * 8]);
#pragma unroll
            for (int n = 0; n < 4; ++n)
                bfr[n] = *reinterpret_cast<const s16x8*>(
                    &Bs[(wc * 64 + n * 16 + rr) * 64 + s * 8]);
#pragma unroll
            for (int m = 0; m < 4; ++m)
#pragma unroll
                for (int n = 0; n < 4; ++n)
                    acc[m][n] = __builtin_amdgcn_mfma_f32_16x16x32_bf16(
                        af[m], bfr[n], acc[m][n], 0, 0, 0);
        }
    }

    // C/D map: col=lane&15, row=(lane>>4)*4+j
#pragma unroll
    for (int m = 0; m < 4; ++m) {
#pragma unroll
        for (int n = 0; n < 4; ++n) {
            const int col = n0 + wc * 64 + n * 16 + rr;
            const float bv = bias[col];
#pragma unroll
            for (int j = 0; j < 4; ++j) {
                const int row = m0 + wr * 64 + m * 16 + g * 4 + j;
                const float v = acc[m][n][j] + bv;
                if constexpr (sizeof(OutT) == 2)
                    C[(size_t)row * N + col] = (OutT)f2b(v);
                else
                    C[(size_t)row * N + col] = (OutT)v;
            }
        }
    }
}

// ---------------------------------------------------------------------------
// MFMA causal flash attention, uniform-work pairing.
// Grid (64 bh, 8); block y handles q-tiles y and 15-y (36 kt-iters total each
// -> all blocks finish together). 4 waves x 32 q-rows. Scale 0.125*log2e is
// folded into Q so the exp path is pure ex2. T13 defer-max skips the O-rescale
// when the running max grew by <= 8 (log2 domain).
// ---------------------------------------------------------------------------
__global__ __launch_bounds__(256)
void attn_mfma(const u16* __restrict__ qkv, u16* __restrict__ out)
{
    __shared__ __align__(128) u16 Ks[64 * 64];    // 8 KB
    __shared__ __align__(128) u16 Vt[64 * 64];    // 8 KB
    __shared__ __align__(128) u16 Pl[4 * 2048];   // 16 KB (4 KB per wave)

    const int tid  = threadIdx.x;
    const int lane = tid & 63;
    const int wid  = tid >> 6;
    const int c    = lane & 15;
    const int g    = lane >> 4;

    const int bh = blockIdx.x;        // 0..63
    const int b  = bh >> 4;
    const int h  = bh & 15;
    const int skey = tid >> 3;        // staging: key row 0..31 (+32 second pass)
    const int sb   = tid & 7;         // staging: 16B d-block 0..7
    const u32 pbyte = ((u32)(size_t)(&Pl[0])) + wid * 4096 + lane * 8;
    const float QSC = 0.18033688f;    // 0.125 * log2(e)

    for (int half = 0; half < 2; ++half) {
        const int yt = half ? 15 - (int)blockIdx.y : (int)blockIdx.y;
        const int t0 = yt * 128;
        const int qb0 = t0 + wid * 32;

        // ---- Q fragments, pre-scaled by QSC ----
        s16x8 qf[2][2];
#pragma unroll
        for (int m = 0; m < 2; ++m)
#pragma unroll
            for (int kk = 0; kk < 2; ++kk) {
                u16x8 raw = *reinterpret_cast<const u16x8*>(
                    qkv + (size_t)(b * Tsz + qb0 + m * 16 + c) * (3 * Csz)
                        + h * HD + kk * 32 + g * 8);
                s16x8 qv;
#pragma unroll
                for (int i = 0; i < 8; ++i) qv[i] = (short)f2b(b2f(raw[i]) * QSC);
                qf[m][kk] = qv;
            }

        f32x4 acco[2][4];
#pragma unroll
        for (int m = 0; m < 2; ++m)
#pragma unroll
            for (int dn = 0; dn < 4; ++dn) acco[m][dn] = (f32x4){0.f, 0.f, 0.f, 0.f};
        float mrun[8], lrun[8];
#pragma unroll
        for (int i = 0; i < 8; ++i) { mrun[i] = -1e30f; lrun[i] = 0.f; }

        for (int kt = 0; kt < t0 + 128; kt += 64) {
            // ---- stage K (swizzled b128) + V (transposed scatter) ----
#pragma unroll
            for (int p = 0; p < 2; ++p) {
                const int key = skey + p * 32;
                const u16* gk = qkv + (size_t)(b * Tsz + kt + key) * (3 * Csz)
                                + Csz + h * HD + sb * 8;
                u16x8 kv = *reinterpret_cast<const u16x8*>(gk);
                u16x8 vv = *reinterpret_cast<const u16x8*>(gk + Csz);
                *reinterpret_cast<u16x8*>(&Ks[key * 64 + ((sb ^ (key & 7)) * 8)]) = kv;
#pragma unroll
                for (int i = 0; i < 8; ++i) {
                    const int d = sb * 8 + i;               // swz(d) = i^sb
                    Vt[d * 64 + (key ^ (((i ^ sb) & 7) << 3))] = vv[i];
                }
            }
            __syncthreads();

            if (kt <= qb0 + 31) {     // wave-uniform: skip fully-masked tiles
                // ---- S' = (Q*QSC) K^T  (log2-scaled scores) ----
                f32x4 accS[2][4];
#pragma unroll
                for (int m = 0; m < 2; ++m)
#pragma unroll
                    for (int n = 0; n < 4; ++n) accS[m][n] = (f32x4){0.f, 0.f, 0.f, 0.f};
#pragma unroll
                for (int kk = 0; kk < 2; ++kk) {
                    s16x8 kf[4];
#pragma unroll
                    for (int n = 0; n < 4; ++n) {
                        const int key = n * 16 + c;
                        kf[n] = *reinterpret_cast<const s16x8*>(
                            &Ks[key * 64 + (((kk * 4 + g) ^ (c & 7)) * 8)]);
                    }
#pragma unroll
                    for (int m = 0; m < 2; ++m)
#pragma unroll
                        for (int n = 0; n < 4; ++n)
                            accS[m][n] = __builtin_amdgcn_mfma_f32_16x16x32_bf16(
                                qf[m][kk], kf[n], accS[m][n], 0, 0, 0);
                }

                // ---- causal mask (diagonal tiles only) ----
                if (kt + 63 > qb0) {
#pragma unroll
                    for (int m = 0; m < 2; ++m)
#pragma unroll
                        for (int n = 0; n < 4; ++n) {
                            const int kgl = kt + n * 16 + c;
#pragma unroll
                            for (int j = 0; j < 4; ++j) {
                                const int qg = qb0 + m * 16 + g * 4 + j;
                                if (kgl > qg) accS[m][n][j] = -1e30f;
                            }
                        }
                }

                // ---- row max (16-lane groups) ----
                float pm[8];
#pragma unroll
                for (int m = 0; m < 2; ++m)
#pragma unroll
                    for (int j = 0; j < 4; ++j)
                        pm[m * 4 + j] = fmaxf(fmaxf(accS[m][0][j], accS[m][1][j]),
                                              fmaxf(accS[m][2][j], accS[m][3][j]));
#pragma unroll
                for (int msk = 1; msk < 16; msk <<= 1)
#pragma unroll
                    for (int i = 0; i < 8; ++i)
                        pm[i] = fmaxf(pm[i], __shfl_xor(pm[i], msk));

                // ---- T13 defer-max: rescale only if max grew by > 8 ----
                int need = 0;
#pragma unroll
                for (int i = 0; i < 8; ++i) need |= (pm[i] > mrun[i] + 8.f);
                if (__any(need)) {
                    float cvec[8];
#pragma unroll
                    for (int i = 0; i < 8; ++i) {
                        const float mn = fmaxf(mrun[i], pm[i]);
                        cvec[i] = ex2(mrun[i] - mn);
                        mrun[i] = mn;
                        lrun[i] *= cvec[i];
                    }
#pragma unroll
                    for (int m = 0; m < 2; ++m)
#pragma unroll
                        for (int dn = 0; dn < 4; ++dn)
#pragma unroll
                            for (int j = 0; j < 4; ++j)
                                acco[m][dn][j] *= cvec[m * 4 + j];
                }

                // ---- P = 2^(S'-m'); pack bf16 (cvt_pk); tr-read slot layout ----
#pragma unroll
                for (int m = 0; m < 2; ++m)
#pragma unroll
                    for (int n = 0; n < 4; ++n) {
                        float pv[4];
#pragma unroll
                        for (int j = 0; j < 4; ++j) {
                            pv[j] = ex2(accS[m][n][j] - mrun[m * 4 + j]);
                            lrun[m * 4 + j] += pv[j];
                        }
                        const u32 w0 = cvtpk(pv[0], pv[1]);
                        const u32 w1 = cvtpk(pv[2], pv[3]);
                        const int slot = (n >> 1) * 32 + ((c >> 2) & 1) * 16
                                       + ((n & 1) * 2 + (c >> 3)) * 4 + (c & 3);
                        *reinterpret_cast<u32x2*>(
                            &Pl[wid * 2048 + m * 1024 + slot * 16 + g * 4]) = (u32x2){w0, w1};
                    }
                asm volatile("s_waitcnt lgkmcnt(0)" ::: "memory");
                __builtin_amdgcn_sched_barrier(0);

                // ---- hardware transpose reads: P A-frags ----
                u16x4 t000, t001, t010, t011, t100, t101, t110, t111;
                asm volatile("ds_read_b64_tr_b16 %0, %1"             : "=v"(t000) : "v"(pbyte));
                asm volatile("ds_read_b64_tr_b16 %0, %1 offset:512"  : "=v"(t001) : "v"(pbyte));
                asm volatile("ds_read_b64_tr_b16 %0, %1 offset:1024" : "=v"(t010) : "v"(pbyte));
                asm volatile("ds_read_b64_tr_b16 %0, %1 offset:1536" : "=v"(t011) : "v"(pbyte));
                asm volatile("ds_read_b64_tr_b16 %0, %1 offset:2048" : "=v"(t100) : "v"(pbyte));
                asm volatile("ds_read_b64_tr_b16 %0, %1 offset:2560" : "=v"(t101) : "v"(pbyte));
                asm volatile("ds_read_b64_tr_b16 %0, %1 offset:3072" : "=v"(t110) : "v"(pbyte));
                asm volatile("ds_read_b64_tr_b16 %0, %1 offset:3584" : "=v"(t111) : "v"(pbyte));
                asm volatile("s_waitcnt lgkmcnt(0)" ::: "memory");
                __builtin_amdgcn_sched_barrier(0);

                s16x8 pa[2][2];
#pragma unroll
                for (int q = 0; q < 4; ++q) {
                    pa[0][0][q] = (short)t000[q]; pa[0][0][q + 4] = (short)t001[q];
                    pa[0][1][q] = (short)t010[q]; pa[0][1][q + 4] = (short)t011[q];
                    pa[1][0][q] = (short)t100[q]; pa[1][0][q + 4] = (short)t101[q];
                    pa[1][1][q] = (short)t110[q]; pa[1][1][q + 4] = (short)t111[q];
                }

                // ---- O += P V ----
#pragma unroll
                for (int kk = 0; kk < 2; ++kk) {
                    s16x8 vf[4];
#pragma unroll
                    for (int dn = 0; dn < 4; ++dn) {
                        const int d = dn * 16 + c;
                        const int swz = (c & 7) ^ ((dn * 2 + (c >> 3)) & 7);
                        vf[dn] = *reinterpret_cast<const s16x8*>(
                            &Vt[d * 64 + (((kk * 4 + g) ^ swz) * 8)]);
                    }
#pragma unroll
                    for (int m = 0; m < 2; ++m)
#pragma unroll
                        for (int dn = 0; dn < 4; ++dn)
                            acco[m][dn] = __builtin_amdgcn_mfma_f32_16x16x32_bf16(
                                pa[m][kk], vf[dn], acco[m][dn], 0, 0, 0);
                }
            }
            __syncthreads();
        }

        // ---- finalize this q-tile ----
#pragma unroll
        for (int msk = 1; msk < 16; msk <<= 1)
#pragma unroll
            for (int i = 0; i < 8; ++i)
                lrun[i] += __shfl_xor(lrun[i], msk);
        float inv[8];
#pragma unroll
        for (int i = 0; i < 8; ++i) inv[i] = 1.f / lrun[i];
#pragma unroll
        for (int m = 0; m < 2; ++m)
#pragma unroll
            for (int dn = 0; dn < 4; ++dn)
#pragma unroll
                for (int j = 0; j < 4; ++j) {
                    const int q = qb0 + m * 16 + g * 4 + j;
                    out[(size_t)(b * Tsz + q) * Csz + h * HD + dn * 16 + c] =
                        f2b(acco[m][dn][j] * inv[m * 4 + j]);
                }
    }
}

// ---------------------------------------------------------------------------
extern "C" void kernel_launch(void* const* d_in, const int* in_sizes, int n_in,
                              void* d_out, int out_size, void* d_ws, size_t ws_size,
                              hipStream_t stream) {
    const float* x      = (const float*)d_in[0];   // [B,T,C]
    const float* w_attn = (const float*)d_in[1];   // [C,3C]
    const float* b_attn = (const float*)d_in[2];   // [3C]
    const float* w_proj = (const float*)d_in[3];   // [C,C]
    const float* b_proj = (const float*)d_in[4];   // [C]
    float* out = (float*)d_out;                    // [B,T,C] fp32

    // ws: qkv_bf 48M | x_bf 16M | ao_bf 16M | wat 6M | wpt 2M
    char* w = (char*)d_ws;
    u16* qkv_bf = (u16*)w;  w += (size_t)NT * 3 * Csz * 2;
    u16* x_bf   = (u16*)w;  w += (size_t)NT * Csz * 2;
    u16* ao_bf  = (u16*)w;  w += (size_t)NT * Csz * 2;
    u16* wat    = (u16*)w;  w += (size_t)3 * Csz * Csz * 2;
    u16* wpt    = (u16*)w;

    conv_f32_bf16<<<(NT * Csz / 8 + 255) / 256, 256, 0, stream>>>(x, x_bf, NT * Csz / 8);
    transpose_conv<<<dim3(3 * Csz / 32, Csz / 32), 256, 0, stream>>>(w_attn, wat, Csz, 3 * Csz);
    transpose_conv<<<dim3(Csz / 32, Csz / 32), 256, 0, stream>>>(w_proj, wpt, Csz, Csz);

    gemm_bf16<u16><<<dim3(3 * Csz / 128, NT / 128), 256, 0, stream>>>(
        x_bf, wat, b_attn, qkv_bf, NT, 3 * Csz, Csz);

    attn_mfma<<<dim3(Bsz * NH, 8), 256, 0, stream>>>(qkv_bf, ao_bf);

    gemm_bf16<float><<<dim3(Csz / 128, NT / 128), 256, 0, stream>>>(
        ao_bf, wpt, b_proj, out, NT, Csz, Csz);
}